// Round 6
// baseline (549.731 us; speedup 1.0000x reference)
//
#include <hip/hip_runtime.h>

// Segment-sum via counting-sort CSR + gather-reduce.
// R6: hist+rank (R5) -> hierarchical 3-kernel scan (R4) -> deterministic
// scatter (R5) -> NEW reduce: 16 rows per block, coalesced ids stream,
// per-edge row via 4-step binary search in LDS, LDS f32 atomic accumulate.

#define TILE 1024  // scan tile: 256 threads x 4 elems

__global__ __launch_bounds__(256) void hist_rank_kernel(
    const int* __restrict__ edge0, int* __restrict__ counts,
    int* __restrict__ rank, int E)
{
    int t = blockIdx.x * blockDim.x + threadIdx.x;
    int base = t * 4;
    if (base + 3 < E) {
        int4 r = ((const int4*)edge0)[t];
        int4 k;
        k.x = atomicAdd(&counts[r.x], 1);
        k.y = atomicAdd(&counts[r.y], 1);
        k.z = atomicAdd(&counts[r.z], 1);
        k.w = atomicAdd(&counts[r.w], 1);
        ((int4*)rank)[t] = k;
    } else {
        for (int i = base; i < E; ++i) rank[i] = atomicAdd(&counts[edge0[i]], 1);
    }
}

__global__ __launch_bounds__(256) void scan_partial(
    const int* __restrict__ counts, int* __restrict__ tileSum, int N)
{
    __shared__ int wsum[4];
    int t = threadIdx.x;
    int base = blockIdx.x * TILE + t * 4;
    int s = 0;
    #pragma unroll
    for (int k = 0; k < 4; ++k) {
        int i = base + k;
        if (i < N) s += counts[i];
    }
    for (int off = 1; off < 64; off <<= 1) s += __shfl_xor(s, off);
    if ((t & 63) == 0) wsum[t >> 6] = s;
    __syncthreads();
    if (t == 0) tileSum[blockIdx.x] = wsum[0] + wsum[1] + wsum[2] + wsum[3];
}

// numTiles must be <= 64 (N <= 65536; here N = 50000 -> 49 tiles).
__global__ __launch_bounds__(64) void scan_tiles(
    const int* __restrict__ tileSum, int* __restrict__ tileOff, int numTiles,
    int* __restrict__ offsets, int N, int E)
{
    int t = threadIdx.x;
    int v0 = (t < numTiles) ? tileSum[t] : 0;
    int v = v0;
    for (int off = 1; off < 64; off <<= 1) {
        int u = __shfl_up(v, off);
        if (t >= off) v += u;
    }
    if (t < numTiles) tileOff[t] = v - v0;   // exclusive
    if (t == 0) offsets[N] = E;
}

__global__ __launch_bounds__(256) void scan_final(
    const int* __restrict__ counts, const int* __restrict__ tileOff,
    int* __restrict__ offsets, int N)
{
    __shared__ int wtot[4];
    int t = threadIdx.x;
    int lane = t & 63, wv = t >> 6;
    int base = blockIdx.x * TILE + t * 4;
    int c[4]; int s = 0;
    #pragma unroll
    for (int k = 0; k < 4; ++k) {
        int i = base + k;
        c[k] = (i < N) ? counts[i] : 0;
        s += c[k];
    }
    int inc = s;
    for (int off = 1; off < 64; off <<= 1) {
        int u = __shfl_up(inc, off);
        if (lane >= off) inc += u;
    }
    if (lane == 63) wtot[wv] = inc;
    __syncthreads();
    int wpre = 0;
    for (int w = 0; w < wv; ++w) wpre += wtot[w];
    int pre = tileOff[blockIdx.x] + wpre + (inc - s);
    #pragma unroll
    for (int k = 0; k < 4; ++k) {
        int i = base + k;
        if (i < N) offsets[i] = pre;
        pre += c[k];
    }
}

// Deterministic scatter: no atomics, no dependence chains.
__global__ __launch_bounds__(256) void scatter_kernel(
    const int* __restrict__ edge0, const int* __restrict__ rank,
    const int* __restrict__ offsets, int* __restrict__ ids, int E)
{
    int t = blockIdx.x * blockDim.x + threadIdx.x;
    int base = t * 4;
    if (base + 3 < E) {
        int4 r = ((const int4*)edge0)[t];
        int4 k = ((const int4*)rank)[t];
        ids[offsets[r.x] + k.x] = base;
        ids[offsets[r.y] + k.y] = base + 1;
        ids[offsets[r.z] + k.z] = base + 2;
        ids[offsets[r.w] + k.w] = base + 3;
    } else {
        for (int i = base; i < E; ++i) ids[offsets[edge0[i]] + rank[i]] = i;
    }
}

// 16 rows per block. 256 threads = 16 edge-slots x 16 float4-groups.
// Block streams ids[beg..end) coalesced (16 edges in flight / round);
// each thread binary-searches its edge's row in the 17-entry LDS boundary
// table and LDS-atomicAdds its float4 into the 16x64 accumulator tile.
__global__ __launch_bounds__(256) void reduce_kernel(
    const int* __restrict__ offsets, const int* __restrict__ ids,
    const float4* __restrict__ w4, float4* __restrict__ out4, int N)
{
    __shared__ float acc[16][64];   // 4 KB tile
    __shared__ int offs[17];
    int t = threadIdx.x;
    int r0 = blockIdx.x * 16;
    int rlim = min(16, N - r0);
    if (t < 17) offs[t] = offsets[r0 + (t < rlim ? t : rlim)];
    ((float4*)acc)[t] = make_float4(0.f, 0.f, 0.f, 0.f);  // 256 float4 = tile
    __syncthreads();

    int beg = offs[0], end = offs[16];
    int slot = t >> 4, q = t & 15;
    for (int j = beg + slot; j < end; j += 16) {
        int e = ids[j];                         // coalesced across slots
        float4 w = w4[(size_t)e * 16 + q];      // 256B gather per edge
        // row = largest r with offs[r] <= j (offs padded to end for r>=rlim)
        int row = 0;
        if (offs[row + 8] <= j) row += 8;
        if (offs[row + 4] <= j) row += 4;
        if (offs[row + 2] <= j) row += 2;
        if (offs[row + 1] <= j) row += 1;
        float* a = &acc[row][q * 4];
        atomicAdd(a + 0, w.x);
        atomicAdd(a + 1, w.y);
        atomicAdd(a + 2, w.z);
        atomicAdd(a + 3, w.w);
    }
    __syncthreads();
    if (slot < rlim)
        out4[(size_t)(r0 + slot) * 16 + q] = *(const float4*)&acc[slot][q * 4];
}

extern "C" void kernel_launch(void* const* d_in, const int* in_sizes, int n_in,
                              void* d_out, int out_size, void* d_ws, size_t ws_size,
                              hipStream_t stream) {
    const int*   edge   = (const int*)d_in[0];     // (2,E) int32; rows = edge[0,:]
    const float* edge_w = (const float*)d_in[1];   // (E, 64) float32
    int E = in_sizes[0] / 2;
    int N = out_size / 64;
    int numTiles = (N + TILE - 1) / TILE;          // 49 for N=50000 (must be <=64)

    // Workspace (int32): [counts N][offsets N+1][rank E][ids E][tileSum 64][tileOff 64]
    int* counts  = (int*)d_ws;
    int* offsets = counts + N;
    int* rank    = offsets + N + 1;
    int* ids     = rank + E;
    int* tileSum = ids + E;
    int* tileOff = tileSum + 64;

    (void)hipMemsetAsync(counts, 0, (size_t)N * sizeof(int), stream);

    int blocksE = (E + 1023) / 1024;               // 4 edges per thread
    hist_rank_kernel<<<blocksE, 256, 0, stream>>>(edge, counts, rank, E);
    scan_partial<<<numTiles, 256, 0, stream>>>(counts, tileSum, N);
    scan_tiles<<<1, 64, 0, stream>>>(tileSum, tileOff, numTiles, offsets, N, E);
    scan_final<<<numTiles, 256, 0, stream>>>(counts, tileOff, offsets, N);
    scatter_kernel<<<blocksE, 256, 0, stream>>>(edge, rank, offsets, ids, E);

    int blocksR = (N + 15) / 16;                   // 16 rows per block
    reduce_kernel<<<blocksR, 256, 0, stream>>>(offsets, ids, (const float4*)edge_w,
                                               (float4*)d_out, N);
}

// Round 7
// 385.606 us; speedup vs baseline: 1.4256x; 1.4256x over previous
//
#include <hip/hip_runtime.h>

// Segment-sum via counting-sort CSR + gather-reduce.
// R7 = R4 pipeline (hist -> 3-kernel hierarchical scan -> memcpy cursor ->
// atomic scatter) with a deeper-ILP reduce: 1 wave/row, 8 edge-slots/wave,
// 2 float4 per lane, unroll x2 => 32 edge_w loads in flight per wave.

#define TILE 1024  // scan tile: 256 threads x 4 elems

__global__ __launch_bounds__(256) void hist_kernel(
    const int* __restrict__ edge0, int* __restrict__ counts, int E)
{
    int t = blockIdx.x * blockDim.x + threadIdx.x;
    int base = t * 4;
    if (base + 3 < E) {
        int4 r = ((const int4*)edge0)[t];
        atomicAdd(&counts[r.x], 1);
        atomicAdd(&counts[r.y], 1);
        atomicAdd(&counts[r.z], 1);
        atomicAdd(&counts[r.w], 1);
    } else {
        for (int i = base; i < E; ++i) atomicAdd(&counts[edge0[i]], 1);
    }
}

__global__ __launch_bounds__(256) void scan_partial(
    const int* __restrict__ counts, int* __restrict__ tileSum, int N)
{
    __shared__ int wsum[4];
    int t = threadIdx.x;
    int base = blockIdx.x * TILE + t * 4;
    int s = 0;
    #pragma unroll
    for (int k = 0; k < 4; ++k) {
        int i = base + k;
        if (i < N) s += counts[i];
    }
    for (int off = 1; off < 64; off <<= 1) s += __shfl_xor(s, off);
    if ((t & 63) == 0) wsum[t >> 6] = s;
    __syncthreads();
    if (t == 0) tileSum[blockIdx.x] = wsum[0] + wsum[1] + wsum[2] + wsum[3];
}

// numTiles must be <= 64 (N <= 65536; here N = 50000 -> 49 tiles).
__global__ __launch_bounds__(64) void scan_tiles(
    const int* __restrict__ tileSum, int* __restrict__ tileOff, int numTiles,
    int* __restrict__ offsets, int N, int E)
{
    int t = threadIdx.x;
    int v0 = (t < numTiles) ? tileSum[t] : 0;
    int v = v0;
    for (int off = 1; off < 64; off <<= 1) {
        int u = __shfl_up(v, off);
        if (t >= off) v += u;
    }
    if (t < numTiles) tileOff[t] = v - v0;   // exclusive
    if (t == 0) offsets[N] = E;
}

__global__ __launch_bounds__(256) void scan_final(
    const int* __restrict__ counts, const int* __restrict__ tileOff,
    int* __restrict__ offsets, int N)
{
    __shared__ int wtot[4];
    int t = threadIdx.x;
    int lane = t & 63, wv = t >> 6;
    int base = blockIdx.x * TILE + t * 4;
    int c[4]; int s = 0;
    #pragma unroll
    for (int k = 0; k < 4; ++k) {
        int i = base + k;
        c[k] = (i < N) ? counts[i] : 0;
        s += c[k];
    }
    int inc = s;
    for (int off = 1; off < 64; off <<= 1) {
        int u = __shfl_up(inc, off);
        if (lane >= off) inc += u;
    }
    if (lane == 63) wtot[wv] = inc;
    __syncthreads();
    int wpre = 0;
    for (int w = 0; w < wv; ++w) wpre += wtot[w];
    int pre = tileOff[blockIdx.x] + wpre + (inc - s);
    #pragma unroll
    for (int k = 0; k < 4; ++k) {
        int i = base + k;
        if (i < N) offsets[i] = pre;
        pre += c[k];
    }
}

__global__ __launch_bounds__(256) void scatter_kernel(
    const int* __restrict__ edge0, int* __restrict__ cursor,
    int* __restrict__ ids, int E)
{
    int t = blockIdx.x * blockDim.x + threadIdx.x;
    int base = t * 4;
    if (base + 3 < E) {
        int4 r = ((const int4*)edge0)[t];
        ids[atomicAdd(&cursor[r.x], 1)] = base;
        ids[atomicAdd(&cursor[r.y], 1)] = base + 1;
        ids[atomicAdd(&cursor[r.z], 1)] = base + 2;
        ids[atomicAdd(&cursor[r.w], 1)] = base + 3;
    } else {
        for (int i = base; i < E; ++i) ids[atomicAdd(&cursor[edge0[i]], 1)] = i;
    }
}

// 1 wave per row. lane = 8*sub + g: 8 edge-slots (sub), lane covers features
// [8g, 8g+8) as 2 float4. Main loop: 2 edges/slot -> 16 edges, 32 float4
// loads in flight per wave.
__global__ __launch_bounds__(256) void reduce_kernel(
    const int* __restrict__ offsets, const int* __restrict__ ids,
    const float4* __restrict__ w4, float4* __restrict__ out4, int N)
{
    int row = blockIdx.x * 4 + (threadIdx.x >> 6);
    if (row >= N) return;
    int lane = threadIdx.x & 63;
    int sub = lane >> 3, g = lane & 7;       // sub: edge-slot, g: feature-octet
    int beg = offsets[row], end = offsets[row + 1];
    float4 a0 = make_float4(0.f, 0.f, 0.f, 0.f);
    float4 a1 = make_float4(0.f, 0.f, 0.f, 0.f);
    int j = beg + sub;
    for (; j + 8 < end; j += 16) {           // 16 edges per wave-iter
        int e0 = ids[j], e1 = ids[j + 8];
        float4 w00 = w4[(size_t)e0 * 16 + g * 2];
        float4 w01 = w4[(size_t)e0 * 16 + g * 2 + 1];
        float4 w10 = w4[(size_t)e1 * 16 + g * 2];
        float4 w11 = w4[(size_t)e1 * 16 + g * 2 + 1];
        a0.x += w00.x + w10.x; a0.y += w00.y + w10.y;
        a0.z += w00.z + w10.z; a0.w += w00.w + w10.w;
        a1.x += w01.x + w11.x; a1.y += w01.y + w11.y;
        a1.z += w01.z + w11.z; a1.w += w01.w + w11.w;
    }
    if (j < end) {                           // tail: up to 8 edges
        int e = ids[j];
        float4 w0 = w4[(size_t)e * 16 + g * 2];
        float4 w1 = w4[(size_t)e * 16 + g * 2 + 1];
        a0.x += w0.x; a0.y += w0.y; a0.z += w0.z; a0.w += w0.w;
        a1.x += w1.x; a1.y += w1.y; a1.z += w1.z; a1.w += w1.w;
    }
    // combine the 8 edge-slots: xor 8, 16, 32
    #pragma unroll
    for (int m = 8; m < 64; m <<= 1) {
        a0.x += __shfl_xor(a0.x, m); a0.y += __shfl_xor(a0.y, m);
        a0.z += __shfl_xor(a0.z, m); a0.w += __shfl_xor(a0.w, m);
        a1.x += __shfl_xor(a1.x, m); a1.y += __shfl_xor(a1.y, m);
        a1.z += __shfl_xor(a1.z, m); a1.w += __shfl_xor(a1.w, m);
    }
    if (sub == 0) {
        out4[(size_t)row * 16 + g * 2]     = a0;
        out4[(size_t)row * 16 + g * 2 + 1] = a1;
    }
}

extern "C" void kernel_launch(void* const* d_in, const int* in_sizes, int n_in,
                              void* d_out, int out_size, void* d_ws, size_t ws_size,
                              hipStream_t stream) {
    const int*   edge   = (const int*)d_in[0];     // (2,E) int32; rows = edge[0,:]
    const float* edge_w = (const float*)d_in[1];   // (E, 64) float32
    int E = in_sizes[0] / 2;
    int N = out_size / 64;
    int numTiles = (N + TILE - 1) / TILE;          // 49 for N=50000 (must be <=64)

    // Workspace (int32): [counts N][offsets N+1][cursor N][ids E][tileSum 64][tileOff 64]
    int* counts  = (int*)d_ws;
    int* offsets = counts + N;
    int* cursor  = offsets + N + 1;
    int* ids     = cursor + N;
    int* tileSum = ids + E;
    int* tileOff = tileSum + 64;

    (void)hipMemsetAsync(counts, 0, (size_t)N * sizeof(int), stream);

    int blocksE = (E + 1023) / 1024;               // 4 edges per thread
    hist_kernel<<<blocksE, 256, 0, stream>>>(edge, counts, E);
    scan_partial<<<numTiles, 256, 0, stream>>>(counts, tileSum, N);
    scan_tiles<<<1, 64, 0, stream>>>(tileSum, tileOff, numTiles, offsets, N, E);
    scan_final<<<numTiles, 256, 0, stream>>>(counts, tileOff, offsets, N);
    (void)hipMemcpyAsync(cursor, offsets, (size_t)N * sizeof(int),
                         hipMemcpyDeviceToDevice, stream);
    scatter_kernel<<<blocksE, 256, 0, stream>>>(edge, cursor, ids, E);

    int blocksR = (N + 3) / 4;
    reduce_kernel<<<blocksR, 256, 0, stream>>>(offsets, ids, (const float4*)edge_w,
                                               (float4*)d_out, N);
}

// Round 8
// 351.422 us; speedup vs baseline: 1.5643x; 1.0973x over previous
//
#include <hip/hip_runtime.h>

// Segment-sum via counting-sort CSR + gather-reduce.
// R8: 6 dispatches. hist+rank (atomic returns once) -> scan_partial ->
// scan_final (inline redundant tile-scan, no scan_tiles dispatch) ->
// deterministic scatter (pure stores) -> R7 deep-ILP reduce.

#define TILE 1024  // scan tile: 256 threads x 4 elems

__global__ __launch_bounds__(256) void hist_rank_kernel(
    const int* __restrict__ edge0, int* __restrict__ counts,
    int* __restrict__ rank, int E)
{
    int t = blockIdx.x * blockDim.x + threadIdx.x;
    int base = t * 4;
    if (base + 3 < E) {
        int4 r = ((const int4*)edge0)[t];
        int4 k;
        k.x = atomicAdd(&counts[r.x], 1);
        k.y = atomicAdd(&counts[r.y], 1);
        k.z = atomicAdd(&counts[r.z], 1);
        k.w = atomicAdd(&counts[r.w], 1);
        ((int4*)rank)[t] = k;
    } else {
        for (int i = base; i < E; ++i) rank[i] = atomicAdd(&counts[edge0[i]], 1);
    }
}

__global__ __launch_bounds__(256) void scan_partial(
    const int* __restrict__ counts, int* __restrict__ tileSum, int N)
{
    __shared__ int wsum[4];
    int t = threadIdx.x;
    int base = blockIdx.x * TILE + t * 4;
    int s = 0;
    #pragma unroll
    for (int k = 0; k < 4; ++k) {
        int i = base + k;
        if (i < N) s += counts[i];
    }
    for (int off = 1; off < 64; off <<= 1) s += __shfl_xor(s, off);
    if ((t & 63) == 0) wsum[t >> 6] = s;
    __syncthreads();
    if (t == 0) tileSum[blockIdx.x] = wsum[0] + wsum[1] + wsum[2] + wsum[3];
}

// Each block redundantly scans the (<=64) tile sums in its first wave to get
// its own tile prefix, then writes its tile's exclusive offsets.
// numTiles must be <= 64 (N <= 65536; here N = 50000 -> 49 tiles).
__global__ __launch_bounds__(256) void scan_final(
    const int* __restrict__ counts, const int* __restrict__ tileSum,
    int* __restrict__ offsets, int N, int E, int numTiles)
{
    __shared__ int wtot[4];
    __shared__ int tilePre;
    int t = threadIdx.x;
    int lane = t & 63, wv = t >> 6;

    if (t < 64) {                            // wave 0: scan tile sums
        int v0 = (t < numTiles) ? tileSum[t] : 0;
        int v = v0;
        #pragma unroll
        for (int off = 1; off < 64; off <<= 1) {
            int u = __shfl_up(v, off);
            if (t >= off) v += u;
        }
        if (t == blockIdx.x) tilePre = v - v0;   // exclusive prefix of this tile
    }
    if (blockIdx.x == 0 && t == 0) offsets[N] = E;

    int base = blockIdx.x * TILE + t * 4;
    int c[4]; int s = 0;
    #pragma unroll
    for (int k = 0; k < 4; ++k) {
        int i = base + k;
        c[k] = (i < N) ? counts[i] : 0;
        s += c[k];
    }
    int inc = s;
    #pragma unroll
    for (int off = 1; off < 64; off <<= 1) {
        int u = __shfl_up(inc, off);
        if (lane >= off) inc += u;
    }
    if (lane == 63) wtot[wv] = inc;
    __syncthreads();
    int wpre = 0;
    for (int w = 0; w < wv; ++w) wpre += wtot[w];
    int pre = tilePre + wpre + (inc - s);
    #pragma unroll
    for (int k = 0; k < 4; ++k) {
        int i = base + k;
        if (i < N) offsets[i] = pre;
        pre += c[k];
    }
}

// Deterministic scatter: pure loads + stores, no atomics.
__global__ __launch_bounds__(256) void scatter_kernel(
    const int* __restrict__ edge0, const int* __restrict__ rank,
    const int* __restrict__ offsets, int* __restrict__ ids, int E)
{
    int t = blockIdx.x * blockDim.x + threadIdx.x;
    int base = t * 4;
    if (base + 3 < E) {
        int4 r = ((const int4*)edge0)[t];
        int4 k = ((const int4*)rank)[t];
        ids[offsets[r.x] + k.x] = base;
        ids[offsets[r.y] + k.y] = base + 1;
        ids[offsets[r.z] + k.z] = base + 2;
        ids[offsets[r.w] + k.w] = base + 3;
    } else {
        for (int i = base; i < E; ++i) ids[offsets[edge0[i]] + rank[i]] = i;
    }
}

// 1 wave per row. lane = 8*sub + g: 8 edge-slots (sub), lane covers features
// [8g, 8g+8) as 2 float4. Main loop: 16 edges, 32 float4 loads in flight.
__global__ __launch_bounds__(256) void reduce_kernel(
    const int* __restrict__ offsets, const int* __restrict__ ids,
    const float4* __restrict__ w4, float4* __restrict__ out4, int N)
{
    int row = blockIdx.x * 4 + (threadIdx.x >> 6);
    if (row >= N) return;
    int lane = threadIdx.x & 63;
    int sub = lane >> 3, g = lane & 7;       // sub: edge-slot, g: feature-octet
    int beg = offsets[row], end = offsets[row + 1];
    float4 a0 = make_float4(0.f, 0.f, 0.f, 0.f);
    float4 a1 = make_float4(0.f, 0.f, 0.f, 0.f);
    int j = beg + sub;
    for (; j + 8 < end; j += 16) {           // 16 edges per wave-iter
        int e0 = ids[j], e1 = ids[j + 8];
        float4 w00 = w4[(size_t)e0 * 16 + g * 2];
        float4 w01 = w4[(size_t)e0 * 16 + g * 2 + 1];
        float4 w10 = w4[(size_t)e1 * 16 + g * 2];
        float4 w11 = w4[(size_t)e1 * 16 + g * 2 + 1];
        a0.x += w00.x + w10.x; a0.y += w00.y + w10.y;
        a0.z += w00.z + w10.z; a0.w += w00.w + w10.w;
        a1.x += w01.x + w11.x; a1.y += w01.y + w11.y;
        a1.z += w01.z + w11.z; a1.w += w01.w + w11.w;
    }
    if (j < end) {                           // tail: up to 8 edges
        int e = ids[j];
        float4 w0 = w4[(size_t)e * 16 + g * 2];
        float4 w1 = w4[(size_t)e * 16 + g * 2 + 1];
        a0.x += w0.x; a0.y += w0.y; a0.z += w0.z; a0.w += w0.w;
        a1.x += w1.x; a1.y += w1.y; a1.z += w1.z; a1.w += w1.w;
    }
    #pragma unroll
    for (int m = 8; m < 64; m <<= 1) {
        a0.x += __shfl_xor(a0.x, m); a0.y += __shfl_xor(a0.y, m);
        a0.z += __shfl_xor(a0.z, m); a0.w += __shfl_xor(a0.w, m);
        a1.x += __shfl_xor(a1.x, m); a1.y += __shfl_xor(a1.y, m);
        a1.z += __shfl_xor(a1.z, m); a1.w += __shfl_xor(a1.w, m);
    }
    if (sub == 0) {
        out4[(size_t)row * 16 + g * 2]     = a0;
        out4[(size_t)row * 16 + g * 2 + 1] = a1;
    }
}

extern "C" void kernel_launch(void* const* d_in, const int* in_sizes, int n_in,
                              void* d_out, int out_size, void* d_ws, size_t ws_size,
                              hipStream_t stream) {
    const int*   edge   = (const int*)d_in[0];     // (2,E) int32; rows = edge[0,:]
    const float* edge_w = (const float*)d_in[1];   // (E, 64) float32
    int E = in_sizes[0] / 2;
    int N = out_size / 64;
    int numTiles = (N + TILE - 1) / TILE;          // 49 for N=50000 (must be <=64)

    // Workspace (int32): [counts N][offsets N+1][rank E][ids E][tileSum 64]
    int* counts  = (int*)d_ws;
    int* offsets = counts + N;
    int* rank    = offsets + N + 1;
    int* ids     = rank + E;
    int* tileSum = ids + E;

    (void)hipMemsetAsync(counts, 0, (size_t)N * sizeof(int), stream);

    int blocksE = (E + 1023) / 1024;               // 4 edges per thread
    hist_rank_kernel<<<blocksE, 256, 0, stream>>>(edge, counts, rank, E);
    scan_partial<<<numTiles, 256, 0, stream>>>(counts, tileSum, N);
    scan_final<<<numTiles, 256, 0, stream>>>(counts, tileSum, offsets, N, E, numTiles);
    scatter_kernel<<<blocksE, 256, 0, stream>>>(edge, rank, offsets, ids, E);

    int blocksR = (N + 3) / 4;
    reduce_kernel<<<blocksR, 256, 0, stream>>>(offsets, ids, (const float4*)edge_w,
                                               (float4*)d_out, N);
}